// Round 17
// baseline (5952.141 us; speedup 1.0000x reference)
//
#include <hip/hip_runtime.h>

// Neural ODE RK4 via MFMA (fp16 split-precision), weights AGPR-resident.
// r1-r16 lesson: all VALU designs are issue/LDS-bound at 2500-4500 cy/eval
// (per-lane weight residency costs a move per MAC; LDS weights cost b128
// streaming). MFMA reads B-operands DIRECTLY from AGPRs (gfx950 unified
// file): weights pinned once via asm "+a", consumed in-place by inline-asm
// v_mfma_f32_16x16x32_f16 -> no per-eval weight movement at all.
// 64 blocks x 512 thr (8 waves); block owns 16 rows (M=16, no M-waste).
// Split: W = Whi + 2^-11*Wlo', x = xhi + 2^-11*xlo' (lo pre-scaled: no
// fp16 denormals). 3 MFMA terms -> per-product rel err ~2^-22 (fp32-class).
// Per eval: GEMM1 16x256x64 (12 mfma/wave) -> tanh -> GEMM2 16x64x256
// (12 mfma/wave, K split across waves) -> LDS reduce -> RK4 update.

typedef _Float16 h8 __attribute__((ext_vector_type(8)));
typedef float f4 __attribute__((ext_vector_type(4)));

#define NB 1024
#define ND 64
#define NH 256
#define RPB 16
#define NBLK 64
#define NTHR 512
#define LO_SC 2048.0f
#define LO_ISC 4.8828125e-4f   // 2^-11

// D = A*B + D; A from VGPR, B from AGPR (weights live there), D in VGPR.
#define MFMA(ACC, A, B) \
  asm volatile("v_mfma_f32_16x16x32_f16 %0, %1, %2, %0" : "+v"(ACC) : "v"(A), "a"(B))
#define PIN_A(X) asm volatile("" : "+a"(X))

__device__ __forceinline__ float fast_tanh(float x) {
    float e = __expf(2.0f * x);
    float r = __builtin_amdgcn_rcpf(e + 1.0f);
    return 1.0f - 2.0f * r;
}

__global__ __launch_bounds__(NTHR, 2)
void node_rk4_mfma(const float* __restrict__ y0,
                   const float* __restrict__ t,
                   const float* __restrict__ W1,
                   const float* __restrict__ b1,
                   const float* __restrict__ W2,
                   const float* __restrict__ b2,
                   float* __restrict__ out, int nsteps)
{
    // A-fragment-layout staging: [kt][lane][j] -> element (m = lane&15,
    // k = kt*32 + (lane>>4)*8 + j). xP: x (K=64, 2 kt). aP: act (K=256, 8 kt).
    __shared__ __align__(16) _Float16 xPh[2][64][8], xPl[2][64][8];   // 4 KB
    __shared__ __align__(16) _Float16 aPh[8][64][8], aPl[8][64][8];   // 16 KB
    __shared__ __align__(16) f4 part[8][4][64];                       // 32 KB
    __shared__ float yst[16][68], kac[16][68];                        // 8.5 KB
    __shared__ float b2c[64];

    const int tid = threadIdx.x;
    const int w = tid >> 6, l = tid & 63;
    const int ln = l & 15, lg = l >> 4;

    // ---- one-time: gather weight fragments, split hi/lo, pin to AGPRs ----
    // B-frag (K32 x N16): lane l holds B[k = kt*32 + lg*8 + j][n = base + ln].
    h8 B1h00,B1h01,B1h10,B1h11, B1l00,B1l01,B1l10,B1l11;   // GEMM1: nt {2w,2w+1} x kt {0,1}
    h8 B2h0,B2h1,B2h2,B2h3, B2l0,B2l1,B2l2,B2l3;           // GEMM2: kt = w, nt 0..3
#define LB1(c,kt,NH_,NL_) { int n_ = ((2*w+(c))<<4) + ln; int kb_ = (kt)*32 + lg*8; \
    _Pragma("unroll") for (int j=0;j<8;++j){ float f_ = W1[(kb_+j)*NH + n_]; \
      _Float16 fh_ = (_Float16)f_; NH_[j]=fh_; NL_[j]=(_Float16)((f_-(float)fh_)*LO_SC);} }
#define LB2(nt,NH_,NL_) { int n_ = ((nt)<<4) + ln; int kb_ = w*32 + lg*8; \
    _Pragma("unroll") for (int j=0;j<8;++j){ float f_ = W2[(kb_+j)*ND + n_]; \
      _Float16 fh_ = (_Float16)f_; NH_[j]=fh_; NL_[j]=(_Float16)((f_-(float)fh_)*LO_SC);} }
    LB1(0,0,B1h00,B1l00) LB1(0,1,B1h01,B1l01)
    LB1(1,0,B1h10,B1l10) LB1(1,1,B1h11,B1l11)
    LB2(0,B2h0,B2l0) LB2(1,B2h1,B2l1) LB2(2,B2h2,B2l2) LB2(3,B2h3,B2l3)
    PIN_A(B1h00); PIN_A(B1h01); PIN_A(B1h10); PIN_A(B1h11);
    PIN_A(B1l00); PIN_A(B1l01); PIN_A(B1l10); PIN_A(B1l11);
    PIN_A(B2h0); PIN_A(B2h1); PIN_A(B2h2); PIN_A(B2h3);
    PIN_A(B2l0); PIN_A(B2l1); PIN_A(B2l2); PIN_A(B2l3);

    const float b1v0 = b1[((2*w)<<4) + ln];
    const float b1v1 = b1[((2*w+1)<<4) + ln];
    if (tid < 64) b2c[tid] = b2[tid];

    // ---- init: y-state, step-0 output, first x pack ----
    if (tid < 256) {
        int nt2 = tid >> 6, lane = tid & 63;
        int d = (nt2<<4) + (lane & 15), mb = (lane >> 4) << 2;
        int kt2 = d >> 5, g = (d >> 3) & 3, j = d & 7;
        size_t rb = (size_t)blockIdx.x * RPB * ND;
        #pragma unroll
        for (int e=0;e<4;++e) {
            int m = mb + e;
            float v = y0[rb + m*ND + d];
            yst[m][d] = v;
            out[rb + m*ND + d] = v;
            _Float16 vh = (_Float16)v;
            xPh[kt2][m + (g<<4)][j] = vh;
            xPl[kt2][m + (g<<4)][j] = (_Float16)((v-(float)vh)*LO_SC);
        }
    }
    __syncthreads();

#define STAGE(ST, DT) do { \
    /* GEMM1: D[16m x 32n-slice] = x @ W1-slice + b1 */ \
    h8 xh0 = *(const h8*)xPh[0][l], xh1 = *(const h8*)xPh[1][l]; \
    h8 xl0 = *(const h8*)xPl[0][l], xl1 = *(const h8*)xPl[1][l]; \
    f4 aH0 = {b1v0,b1v0,b1v0,b1v0}, aH1 = {b1v1,b1v1,b1v1,b1v1}; \
    f4 aL0 = {0.f,0.f,0.f,0.f},     aL1 = {0.f,0.f,0.f,0.f}; \
    MFMA(aH0,xh0,B1h00); MFMA(aH1,xh0,B1h10); \
    MFMA(aL0,xl0,B1h00); MFMA(aL1,xl0,B1h10); \
    MFMA(aL0,xh0,B1l00); MFMA(aL1,xh0,B1l10); \
    MFMA(aH0,xh1,B1h01); MFMA(aH1,xh1,B1h11); \
    MFMA(aL0,xl1,B1h01); MFMA(aL1,xl1,B1h11); \
    MFMA(aL0,xh1,B1l01); MFMA(aL1,xh1,B1l11); \
    /* tanh + scatter into aP (A-frag layout for GEMM2) */ \
    _Pragma("unroll") for (int c=0;c<2;++c) { \
      f4 hh = c ? (aH1 + LO_ISC*aL1) : (aH0 + LO_ISC*aL0); \
      int kk = ((2*w+c)<<4) + ln; \
      int kt2 = kk>>5, g=(kk>>3)&3, j=kk&7; \
      _Pragma("unroll") for (int r=0;r<4;++r) { \
        float a_ = fast_tanh(hh[r]); \
        int lp = (lg*4 + r) + (g<<4); \
        _Float16 ah_ = (_Float16)a_; \
        aPh[kt2][lp][j] = ah_; \
        aPl[kt2][lp][j] = (_Float16)((a_-(float)ah_)*LO_SC); \
      } } \
    __syncthreads(); \
    /* GEMM2: wave w = K-slice w; partials over 4 n-tiles of ND */ \
    { h8 a8 = *(const h8*)aPh[w][l], al8 = *(const h8*)aPl[w][l]; \
      f4 c0={0.f,0.f,0.f,0.f},c1={0.f,0.f,0.f,0.f},c2={0.f,0.f,0.f,0.f},c3={0.f,0.f,0.f,0.f}; \
      f4 d0={0.f,0.f,0.f,0.f},d1={0.f,0.f,0.f,0.f},d2={0.f,0.f,0.f,0.f},d3={0.f,0.f,0.f,0.f}; \
      MFMA(c0,a8,B2h0); MFMA(c1,a8,B2h1); MFMA(c2,a8,B2h2); MFMA(c3,a8,B2h3); \
      MFMA(d0,al8,B2h0); MFMA(d1,al8,B2h1); MFMA(d2,al8,B2h2); MFMA(d3,al8,B2h3); \
      MFMA(d0,a8,B2l0); MFMA(d1,a8,B2l1); MFMA(d2,a8,B2l2); MFMA(d3,a8,B2l3); \
      part[w][0][l] = c0 + LO_ISC*d0; part[w][1][l] = c1 + LO_ISC*d1; \
      part[w][2][l] = c2 + LO_ISC*d2; part[w][3][l] = c3 + LO_ISC*d3; } \
    __syncthreads(); \
    /* reduce 8 K-slices + b2 -> k; RK4 update; pack next x */ \
    if (tid < 256) { \
      int nt2 = tid>>6, lane = tid&63; \
      int d = (nt2<<4) + (lane&15), mb = (lane>>4)<<2; \
      f4 s_ = part[0][nt2][lane]+part[1][nt2][lane]+part[2][nt2][lane]+part[3][nt2][lane] \
            + part[4][nt2][lane]+part[5][nt2][lane]+part[6][nt2][lane]+part[7][nt2][lane]; \
      int kt2 = d>>5, g=(d>>3)&3, j=d&7; \
      float bb = b2c[d]; \
      _Pragma("unroll") for (int e=0;e<4;++e) { \
        int m = mb+e; float kc = s_[e] + bb; float xn; \
        if ((ST)==1)      { kac[m][d] = kc;        xn = yst[m][d] + 0.5f*(DT)*kc; } \
        else if ((ST)==2) { kac[m][d] += 2.0f*kc;  xn = yst[m][d] + 0.5f*(DT)*kc; } \
        else if ((ST)==3) { kac[m][d] += 2.0f*kc;  xn = yst[m][d] + (DT)*kc; } \
        else { float yn = yst[m][d] + ((DT)*(1.0f/6.0f))*(kac[m][d] + kc); \
               yst[m][d] = yn; xn = yn; \
               out[obase + m*ND + d] = yn; } \
        _Float16 xh_ = (_Float16)xn; \
        xPh[kt2][m+(g<<4)][j] = xh_; \
        xPl[kt2][m+(g<<4)][j] = (_Float16)((xn-(float)xh_)*LO_SC); \
      } } \
    __syncthreads(); \
} while(0)

    for (int s = 0; s < nsteps; ++s) {
        float dt = t[s+1] - t[s];
        size_t obase = ((size_t)(s+1))*(NB*ND) + (size_t)blockIdx.x*RPB*ND;
        STAGE(1, dt);
        STAGE(2, dt);
        STAGE(3, dt);
        STAGE(4, dt);
        (void)obase;
    }
}

extern "C" void kernel_launch(void* const* d_in, const int* in_sizes, int n_in,
                              void* d_out, int out_size, void* d_ws, size_t ws_size,
                              hipStream_t stream) {
    const float* y0 = (const float*)d_in[0];
    const float* t  = (const float*)d_in[1];
    const float* W1 = (const float*)d_in[2];
    const float* b1 = (const float*)d_in[3];
    const float* W2 = (const float*)d_in[4];
    const float* b2 = (const float*)d_in[5];
    float* out = (float*)d_out;
    int nsteps = in_sizes[1] - 1;
    hipLaunchKernelGGL(node_rk4_mfma, dim3(NBLK), dim3(NTHR), 0, stream,
                       y0, t, W1, b1, W2, b2, out, nsteps);
}

// Round 18
// 5330.757 us; speedup vs baseline: 1.1166x; 1.1166x over previous
//
#include <hip/hip_runtime.h>

// Neural ODE RK4, fp16 split-precision MFMA, wave-specialized 2-phase pipe.
// r17 (3-phase: GEMM1 | GEMM2-Ksplit | reduce) = 3600cy/eval, all latency.
// r18: G1-waves (w<4) hold W1 frags in AGPRs, do GEMM1+tanh -> aP.
//      G2-waves (w>=4) hold W2 frags FULL-K in AGPRs, do GEMM2 + RK4 with
//      state in registers (D-frag layout) -> pack xP + store out.
// 2 barriers/eval, no reduce stage, no LDS state. 64 blocks x 16 rows.
// Fragment mappings identical to r17 (verified: absmax == fp32 baseline).

typedef _Float16 h8 __attribute__((ext_vector_type(8)));
typedef float f4 __attribute__((ext_vector_type(4)));

#define NB 1024
#define ND 64
#define NH 256
#define RPB 16
#define NBLK 64
#define NTHR 512
#define LO_SC 2048.0f
#define LO_ISC 4.8828125e-4f   // 2^-11

#define MFMA(ACC, A, B) \
  asm volatile("v_mfma_f32_16x16x32_f16 %0, %1, %2, %0" : "+v"(ACC) : "v"(A), "a"(B))
#define PIN_A(X) asm volatile("" : "+a"(X))

#define BSYNC() do { \
    asm volatile("s_waitcnt lgkmcnt(0)" ::: "memory"); \
    __builtin_amdgcn_s_barrier(); \
    asm volatile("" ::: "memory"); \
} while (0)

__device__ __forceinline__ float fast_tanh(float x) {
    float e = __expf(2.0f * x);
    float r = __builtin_amdgcn_rcpf(e + 1.0f);
    return 1.0f - 2.0f * r;
}

__global__ __launch_bounds__(NTHR, 2)
void node_rk4_mfma(const float* __restrict__ y0,
                   const float* __restrict__ t,
                   const float* __restrict__ W1,
                   const float* __restrict__ b1,
                   const float* __restrict__ W2,
                   const float* __restrict__ b2,
                   float* __restrict__ out, int nsteps)
{
    // A-frag staging: [kt][lane][j] holds elem (m = lane&15, k = kt*32 +
    // (lane>>4)*8 + j). xP: K=64 (2 kt). aP: K=256 (8 kt).
    __shared__ __align__(16) _Float16 xPh[2][64][8], xPl[2][64][8];   // 4 KB
    __shared__ __align__(16) _Float16 aPh[8][64][8], aPl[8][64][8];   // 16 KB

    const int tid = threadIdx.x;
    const int w  = tid >> 6, l = tid & 63;
    const int ln = l & 15,  lg = l >> 4;
    const int nevals = 4 * nsteps;

    if (w < 4) {
        // ========== G1: aP = split(tanh(x @ W1 + b1)) ==========
        // W1 B-frags: 4 n-tiles (n = 64w+16nt+ln) x 2 kt; hi + lo = 64 AGPR.
        h8 WH0,WH1,WH2,WH3,WH4,WH5,WH6,WH7;
        h8 WL0,WL1,WL2,WL3,WL4,WL5,WL6,WL7;
#define LG1(NT,KT,H,L) { \
        int n_ = (w<<6) + ((NT)<<4) + ln; \
        int kb_ = (KT)*32 + lg*8; \
        _Pragma("unroll") for (int j=0;j<8;++j) { \
            float f_ = W1[(kb_+j)*NH + n_]; \
            _Float16 fh_ = (_Float16)f_; \
            H[j] = fh_; L[j] = (_Float16)((f_-(float)fh_)*LO_SC); } }
        LG1(0,0,WH0,WL0) LG1(0,1,WH1,WL1)
        LG1(1,0,WH2,WL2) LG1(1,1,WH3,WL3)
        LG1(2,0,WH4,WL4) LG1(2,1,WH5,WL5)
        LG1(3,0,WH6,WL6) LG1(3,1,WH7,WL7)
        PIN_A(WH0);PIN_A(WH1);PIN_A(WH2);PIN_A(WH3);
        PIN_A(WH4);PIN_A(WH5);PIN_A(WH6);PIN_A(WH7);
        PIN_A(WL0);PIN_A(WL1);PIN_A(WL2);PIN_A(WL3);
        PIN_A(WL4);PIN_A(WL5);PIN_A(WL6);PIN_A(WL7);
        const float bv0 = b1[(w<<6) +  0 + ln];
        const float bv1 = b1[(w<<6) + 16 + ln];
        const float bv2 = b1[(w<<6) + 32 + ln];
        const float bv3 = b1[(w<<6) + 48 + ln];

        BSYNC();   // bar0: initial xP ready
        for (int e = 0; e < nevals; ++e) {
            h8 xh0 = *(const h8*)xPh[0][l], xh1 = *(const h8*)xPh[1][l];
            h8 xl0 = *(const h8*)xPl[0][l], xl1 = *(const h8*)xPl[1][l];
#define G1NT(NT, H0,H1,L0,L1, BV) { \
            f4 aH = {BV,BV,BV,BV}; f4 aL = {0.f,0.f,0.f,0.f}; \
            MFMA(aH, xh0, H0); MFMA(aH, xh1, H1); \
            MFMA(aL, xl0, H0); MFMA(aL, xl1, H1); \
            MFMA(aL, xh0, L0); MFMA(aL, xh1, L1); \
            f4 hv = aH + LO_ISC*aL; \
            int n_ = (w<<6) + ((NT)<<4) + ln; \
            int kt_ = n_>>5, g_ = (n_>>3)&3, j_ = n_&7; \
            _Pragma("unroll") for (int r=0;r<4;++r) { \
                float a_ = fast_tanh(hv[r]); \
                _Float16 ah_ = (_Float16)a_; \
                int ld_ = (lg*4+r) + (g_<<4); \
                aPh[kt_][ld_][j_] = ah_; \
                aPl[kt_][ld_][j_] = (_Float16)((a_-(float)ah_)*LO_SC); } }
            G1NT(0, WH0,WH1,WL0,WL1, bv0)
            G1NT(1, WH2,WH3,WL2,WL3, bv1)
            G1NT(2, WH4,WH5,WL4,WL5, bv2)
            G1NT(3, WH6,WH7,WL6,WL7, bv3)
            BSYNC();   // barA: aP visible to G2
            BSYNC();   // barB: next xP visible to G1
        }
    } else {
        // ========== G2: k = a @ W2 + b2; RK4 state in registers ==========
        const int g2 = w - 4;
        const int d  = (g2<<4) + ln;          // owned output dim
        // W2 B-frags: 1 n-tile (n=d), FULL K = 8 kt; hi+lo = 64 AGPR.
        h8 VH0,VH1,VH2,VH3,VH4,VH5,VH6,VH7;
        h8 VL0,VL1,VL2,VL3,VL4,VL5,VL6,VL7;
#define LG2(KT,H,L) { \
        int kb_ = (KT)*32 + lg*8; \
        _Pragma("unroll") for (int j=0;j<8;++j) { \
            float f_ = W2[(kb_+j)*ND + d]; \
            _Float16 fh_ = (_Float16)f_; \
            H[j] = fh_; L[j] = (_Float16)((f_-(float)fh_)*LO_SC); } }
        LG2(0,VH0,VL0) LG2(1,VH1,VL1) LG2(2,VH2,VL2) LG2(3,VH3,VL3)
        LG2(4,VH4,VL4) LG2(5,VH5,VL5) LG2(6,VH6,VL6) LG2(7,VH7,VL7)
        PIN_A(VH0);PIN_A(VH1);PIN_A(VH2);PIN_A(VH3);
        PIN_A(VH4);PIN_A(VH5);PIN_A(VH6);PIN_A(VH7);
        PIN_A(VL0);PIN_A(VL1);PIN_A(VL2);PIN_A(VL3);
        PIN_A(VL4);PIN_A(VL5);PIN_A(VL6);PIN_A(VL7);
        const float b2v = b2[d];

        // RK4 state in D-frag layout: lane holds y[m=4*lg+r][d], r=0..3.
        const size_t rb = (size_t)blockIdx.x * RPB * ND;
        f4 ys, ka;
        #pragma unroll
        for (int r=0;r<4;++r) {
            float v = y0[rb + (size_t)(4*lg+r)*ND + d];
            ys[r] = v;
            out[rb + (size_t)(4*lg+r)*ND + d] = v;   // step-0 output
        }
        const int xkt = g2 >> 1;                 // = d>>5 (uniform)
        const int xg  = (2*g2 + (ln>>3)) & 3;    // = (d>>3)&3
        const int xj  = ln & 7;                  // = d&7
#define PACKX(XV, R) { \
        float xv_ = (XV); \
        _Float16 xh_ = (_Float16)xv_; \
        int ld_ = (lg*4+(R)) + (xg<<4); \
        xPh[xkt][ld_][xj] = xh_; \
        xPl[xkt][ld_][xj] = (_Float16)((xv_-(float)xh_)*LO_SC); }
        #pragma unroll
        for (int r=0;r<4;++r) PACKX(ys[r], r)
        BSYNC();   // bar0

        for (int s = 0; s < nsteps; ++s) {
            float dt = t[s+1] - t[s];
            size_t ob = (size_t)(s+1)*(NB*ND) + rb;
#define G2EVAL(ST) { \
            BSYNC();  /* barA: aP ready */ \
            h8 a0 = *(const h8*)aPh[0][l], a1 = *(const h8*)aPh[1][l]; \
            h8 a2 = *(const h8*)aPh[2][l], a3 = *(const h8*)aPh[3][l]; \
            h8 a4 = *(const h8*)aPh[4][l], a5 = *(const h8*)aPh[5][l]; \
            h8 a6 = *(const h8*)aPh[6][l], a7 = *(const h8*)aPh[7][l]; \
            h8 c0 = *(const h8*)aPl[0][l], c1 = *(const h8*)aPl[1][l]; \
            h8 c2 = *(const h8*)aPl[2][l], c3 = *(const h8*)aPl[3][l]; \
            h8 c4 = *(const h8*)aPl[4][l], c5 = *(const h8*)aPl[5][l]; \
            h8 c6 = *(const h8*)aPl[6][l], c7 = *(const h8*)aPl[7][l]; \
            f4 HA={0.f,0.f,0.f,0.f}, HB=HA, LA=HA, LB=HA, LC=HA, LD=HA; \
            MFMA(HA,a0,VH0); MFMA(HB,a1,VH1); MFMA(HA,a2,VH2); MFMA(HB,a3,VH3); \
            MFMA(HA,a4,VH4); MFMA(HB,a5,VH5); MFMA(HA,a6,VH6); MFMA(HB,a7,VH7); \
            MFMA(LA,c0,VH0); MFMA(LB,c1,VH1); MFMA(LA,c2,VH2); MFMA(LB,c3,VH3); \
            MFMA(LA,c4,VH4); MFMA(LB,c5,VH5); MFMA(LA,c6,VH6); MFMA(LB,c7,VH7); \
            MFMA(LC,a0,VL0); MFMA(LD,a1,VL1); MFMA(LC,a2,VL2); MFMA(LD,a3,VL3); \
            MFMA(LC,a4,VL4); MFMA(LD,a5,VL5); MFMA(LC,a6,VL6); MFMA(LD,a7,VL7); \
            f4 kv = (HA+HB) + LO_ISC*((LA+LB)+(LC+LD)); \
            _Pragma("unroll") for (int r=0;r<4;++r) kv[r] += b2v; \
            f4 xn; \
            if ((ST)==1)      { ka = kv;        xn = ys + (0.5f*dt)*kv; } \
            else if ((ST)==2) { ka += 2.0f*kv;  xn = ys + (0.5f*dt)*kv; } \
            else if ((ST)==3) { ka += 2.0f*kv;  xn = ys + dt*kv; } \
            else { ys = ys + (dt*(1.0f/6.0f))*(ka + kv); xn = ys; \
                   _Pragma("unroll") for (int r=0;r<4;++r) \
                       out[ob + (size_t)(4*lg+r)*ND + d] = ys[r]; } \
            _Pragma("unroll") for (int r=0;r<4;++r) PACKX(xn[r], r) \
            BSYNC();  /* barB: xP ready */ }
            G2EVAL(1)
            G2EVAL(2)
            G2EVAL(3)
            G2EVAL(4)
        }
    }
}

extern "C" void kernel_launch(void* const* d_in, const int* in_sizes, int n_in,
                              void* d_out, int out_size, void* d_ws, size_t ws_size,
                              hipStream_t stream) {
    const float* y0 = (const float*)d_in[0];
    const float* t  = (const float*)d_in[1];
    const float* W1 = (const float*)d_in[2];
    const float* b1 = (const float*)d_in[3];
    const float* W2 = (const float*)d_in[4];
    const float* b2 = (const float*)d_in[5];
    float* out = (float*)d_out;
    int nsteps = in_sizes[1] - 1;
    hipLaunchKernelGGL(node_rk4_mfma, dim3(NBLK), dim3(NTHR), 0, stream,
                       y0, t, W1, b1, W2, b2, out, nsteps);
}

// Round 19
// 5099.168 us; speedup vs baseline: 1.1673x; 1.0454x over previous
//
#include <hip/hip_runtime.h>

// Neural ODE RK4, fp16 split-precision MFMA, wave-specialized 2-phase pipe.
// r19 change vs r18: BUILTIN mfma (not inline asm) -> compiler inserts exact
// hazard waits (not worst-case around opaque asm) and schedules ds_reads
// under MFMAs; all chains 2-dep; scatter/read pointers hoisted.
// G1-waves (w<4): W1 frags (16 h8, pinned) -> GEMM1+tanh -> aP.
// G2-waves (w>=4): W2 frags full-K -> GEMM2 + RK4 state in registers.
// 2 raw barriers/eval. 64 blocks x 512 thr; block owns 16 rows.

typedef _Float16 h8 __attribute__((ext_vector_type(8)));
typedef float f4 __attribute__((ext_vector_type(4)));

#define NB 1024
#define ND 64
#define NH 256
#define RPB 16
#define NBLK 64
#define NTHR 512
#define LO_SC 2048.0f
#define LO_ISC 4.8828125e-4f   // 2^-11

#define MFMA16(A, B, C) __builtin_amdgcn_mfma_f32_16x16x32_f16((A), (B), (C), 0, 0, 0)
#define PIN(X) asm volatile("" : "+v"(X))

#define BSYNC() do { \
    asm volatile("s_waitcnt lgkmcnt(0)" ::: "memory"); \
    __builtin_amdgcn_s_barrier(); \
    asm volatile("" ::: "memory"); \
} while (0)

__device__ __forceinline__ float fast_tanh(float x) {
    float e = __expf(2.0f * x);
    float r = __builtin_amdgcn_rcpf(e + 1.0f);
    return 1.0f - 2.0f * r;
}

__global__ __launch_bounds__(NTHR, 2)
void node_rk4_mfma(const float* __restrict__ y0,
                   const float* __restrict__ t,
                   const float* __restrict__ W1,
                   const float* __restrict__ b1,
                   const float* __restrict__ W2,
                   const float* __restrict__ b2,
                   float* __restrict__ out, int nsteps)
{
    // A-frag staging: [kt][lane][j] = elem (m=lane&15, k=kt*32+(lane>>4)*8+j)
    __shared__ __align__(16) _Float16 xPh[2][64][8], xPl[2][64][8];   // 4 KB
    __shared__ __align__(16) _Float16 aPh[8][64][8], aPl[8][64][8];   // 16 KB

    const int tid = threadIdx.x;
    const int w  = tid >> 6, l = tid & 63;
    const int ln = l & 15,  lg = l >> 4;

    if (w < 4) {
        // ========== G1: aP = split(tanh(x @ W1 + b1)) ==========
        h8 WH0,WH1,WH2,WH3,WH4,WH5,WH6,WH7;
        h8 WL0,WL1,WL2,WL3,WL4,WL5,WL6,WL7;
#define LG1(NT,KT,H,L) { \
        int n_ = (w<<6) + ((NT)<<4) + ln; \
        int kb_ = (KT)*32 + lg*8; \
        _Pragma("unroll") for (int j=0;j<8;++j) { \
            float f_ = W1[(kb_+j)*NH + n_]; \
            _Float16 fh_ = (_Float16)f_; \
            H[j] = fh_; L[j] = (_Float16)((f_-(float)fh_)*LO_SC); } }
        LG1(0,0,WH0,WL0) LG1(0,1,WH1,WL1)
        LG1(1,0,WH2,WL2) LG1(1,1,WH3,WL3)
        LG1(2,0,WH4,WL4) LG1(2,1,WH5,WL5)
        LG1(3,0,WH6,WL6) LG1(3,1,WH7,WL7)
        PIN(WH0);PIN(WH1);PIN(WH2);PIN(WH3);PIN(WH4);PIN(WH5);PIN(WH6);PIN(WH7);
        PIN(WL0);PIN(WL1);PIN(WL2);PIN(WL3);PIN(WL4);PIN(WL5);PIN(WL6);PIN(WL7);
        const float bv0 = b1[(w<<6) +  0 + ln];
        const float bv1 = b1[(w<<6) + 16 + ln];
        const float bv2 = b1[(w<<6) + 32 + ln];
        const float bv3 = b1[(w<<6) + 48 + ln];

        // hoisted scatter pointers (ld = (g<<4)+lg*4 + r; +r is stride 8 halves)
        _Float16 *aph0,*aph1,*aph2,*aph3, *apl0,*apl1,*apl2,*apl3;
#define SPTR(NT, PH, PL) { \
        int n_ = (w<<6) + ((NT)<<4) + ln; \
        int kt_ = n_>>5, g_ = (n_>>3)&3, j_ = n_&7; \
        PH = &aPh[kt_][(g_<<4)+lg*4][j_]; \
        PL = &aPl[kt_][(g_<<4)+lg*4][j_]; }
        SPTR(0,aph0,apl0) SPTR(1,aph1,apl1) SPTR(2,aph2,apl2) SPTR(3,aph3,apl3)
        const h8* xp0h = (const h8*)&xPh[0][l][0];
        const h8* xp1h = (const h8*)&xPh[1][l][0];
        const h8* xp0l = (const h8*)&xPl[0][l][0];
        const h8* xp1l = (const h8*)&xPl[1][l][0];

        BSYNC();   // bar0: initial xP ready
        const int nevals = 4 * nsteps;
        for (int e = 0; e < nevals; ++e) {
            h8 xh0 = *xp0h, xh1 = *xp1h, xl0 = *xp0l, xl1 = *xp1l;
            f4 zz = {0.f, 0.f, 0.f, 0.f};
#define G1NT(PH, PL, HH0, HH1, LL0, LL1, BV) { \
            f4 aH = {BV,BV,BV,BV}; \
            aH = MFMA16(xh0, HH0, aH);  aH = MFMA16(xh1, HH1, aH); \
            f4 aL1 = MFMA16(xl0, HH0, zz); aL1 = MFMA16(xl1, HH1, aL1); \
            f4 aL2 = MFMA16(xh0, LL0, zz); aL2 = MFMA16(xh1, LL1, aL2); \
            f4 hv = aH + LO_ISC*(aL1 + aL2); \
            _Pragma("unroll") for (int r=0;r<4;++r) { \
                float a_ = fast_tanh(hv[r]); \
                _Float16 ah_ = (_Float16)a_; \
                PH[r*8] = ah_; \
                PL[r*8] = (_Float16)((a_-(float)ah_)*LO_SC); } }
            G1NT(aph0, apl0, WH0, WH1, WL0, WL1, bv0)
            G1NT(aph1, apl1, WH2, WH3, WL2, WL3, bv1)
            G1NT(aph2, apl2, WH4, WH5, WL4, WL5, bv2)
            G1NT(aph3, apl3, WH6, WH7, WL6, WL7, bv3)
            BSYNC();   // barA: aP visible to G2
            BSYNC();   // barB: next xP visible to G1
        }
    } else {
        // ========== G2: k = a @ W2 + b2; RK4 state in registers ==========
        const int g2 = w - 4;
        const int d  = (g2<<4) + ln;          // owned output dim
        h8 VH0,VH1,VH2,VH3,VH4,VH5,VH6,VH7;
        h8 VL0,VL1,VL2,VL3,VL4,VL5,VL6,VL7;
#define LG2(KT,H,L) { \
        int kb_ = (KT)*32 + lg*8; \
        _Pragma("unroll") for (int j=0;j<8;++j) { \
            float f_ = W2[(kb_+j)*ND + d]; \
            _Float16 fh_ = (_Float16)f_; \
            H[j] = fh_; L[j] = (_Float16)((f_-(float)fh_)*LO_SC); } }
        LG2(0,VH0,VL0) LG2(1,VH1,VL1) LG2(2,VH2,VL2) LG2(3,VH3,VL3)
        LG2(4,VH4,VL4) LG2(5,VH5,VL5) LG2(6,VH6,VL6) LG2(7,VH7,VL7)
        PIN(VH0);PIN(VH1);PIN(VH2);PIN(VH3);PIN(VH4);PIN(VH5);PIN(VH6);PIN(VH7);
        PIN(VL0);PIN(VL1);PIN(VL2);PIN(VL3);PIN(VL4);PIN(VL5);PIN(VL6);PIN(VL7);
        const float b2v = b2[d];

        // hoisted aP read pointers
        const h8 *pa0 = (const h8*)&aPh[0][l][0], *pa1 = (const h8*)&aPh[1][l][0];
        const h8 *pa2 = (const h8*)&aPh[2][l][0], *pa3 = (const h8*)&aPh[3][l][0];
        const h8 *pa4 = (const h8*)&aPh[4][l][0], *pa5 = (const h8*)&aPh[5][l][0];
        const h8 *pa6 = (const h8*)&aPh[6][l][0], *pa7 = (const h8*)&aPh[7][l][0];
        const h8 *pc0 = (const h8*)&aPl[0][l][0], *pc1 = (const h8*)&aPl[1][l][0];
        const h8 *pc2 = (const h8*)&aPl[2][l][0], *pc3 = (const h8*)&aPl[3][l][0];
        const h8 *pc4 = (const h8*)&aPl[4][l][0], *pc5 = (const h8*)&aPl[5][l][0];
        const h8 *pc6 = (const h8*)&aPl[6][l][0], *pc7 = (const h8*)&aPl[7][l][0];

        // RK4 state in D-frag layout: lane holds y[m=4*lg+r][d].
        const size_t rb = (size_t)blockIdx.x * RPB * ND;
        f4 ys, ka;
        #pragma unroll
        for (int r=0;r<4;++r) {
            float v = y0[rb + (size_t)(4*lg+r)*ND + d];
            ys[r] = v;
            out[rb + (size_t)(4*lg+r)*ND + d] = v;   // step-0 output
        }
        const int xkt = g2 >> 1;
        const int xg  = 2*(g2&1) + (ln>>3);
        const int xj  = ln & 7;
        _Float16* xph = &xPh[xkt][(xg<<4)+lg*4][xj];
        _Float16* xpl = &xPl[xkt][(xg<<4)+lg*4][xj];
#define PACKX(XV, R) { \
        float xv_ = (XV); \
        _Float16 xh_ = (_Float16)xv_; \
        xph[(R)*8] = xh_; \
        xpl[(R)*8] = (_Float16)((xv_-(float)xh_)*LO_SC); }
        #pragma unroll
        for (int r=0;r<4;++r) PACKX(ys[r], r)
        BSYNC();   // bar0

        for (int s = 0; s < nsteps; ++s) {
            float dt = t[s+1] - t[s];
            size_t ob = (size_t)(s+1)*(NB*ND) + rb;
#define G2EVAL(ST) { \
            BSYNC();  /* barA: aP ready */ \
            h8 a0=*pa0,a1=*pa1,a2=*pa2,a3=*pa3,a4=*pa4,a5=*pa5,a6=*pa6,a7=*pa7; \
            h8 c0=*pc0,c1=*pc1,c2=*pc2,c3=*pc3,c4=*pc4,c5=*pc5,c6=*pc6,c7=*pc7; \
            f4 zz = {0.f,0.f,0.f,0.f}; \
            f4 HA=MFMA16(a0,VH0,zz), HB=MFMA16(a1,VH1,zz); \
            f4 HC=MFMA16(a2,VH2,zz), HD=MFMA16(a3,VH3,zz); \
            HA=MFMA16(a4,VH4,HA); HB=MFMA16(a5,VH5,HB); \
            HC=MFMA16(a6,VH6,HC); HD=MFMA16(a7,VH7,HD); \
            f4 LA=MFMA16(c0,VH0,zz), LB=MFMA16(c1,VH1,zz); \
            f4 LC=MFMA16(c2,VH2,zz), LD=MFMA16(c3,VH3,zz); \
            LA=MFMA16(c4,VH4,LA); LB=MFMA16(c5,VH5,LB); \
            LC=MFMA16(c6,VH6,LC); LD=MFMA16(c7,VH7,LD); \
            f4 MA=MFMA16(a0,VL0,zz), MB=MFMA16(a1,VL1,zz); \
            f4 MC=MFMA16(a2,VL2,zz), MD=MFMA16(a3,VL3,zz); \
            MA=MFMA16(a4,VL4,MA); MB=MFMA16(a5,VL5,MB); \
            MC=MFMA16(a6,VL6,MC); MD=MFMA16(a7,VL7,MD); \
            f4 kv = ((HA+HB)+(HC+HD)) \
                  + LO_ISC*(((LA+LB)+(LC+LD)) + ((MA+MB)+(MC+MD))); \
            _Pragma("unroll") for (int r=0;r<4;++r) kv[r] += b2v; \
            f4 xn; \
            if ((ST)==1)      { ka = kv;        xn = ys + (0.5f*dt)*kv; } \
            else if ((ST)==2) { ka += 2.0f*kv;  xn = ys + (0.5f*dt)*kv; } \
            else if ((ST)==3) { ka += 2.0f*kv;  xn = ys + dt*kv; } \
            else { ys = ys + (dt*(1.0f/6.0f))*(ka + kv); xn = ys; \
                   _Pragma("unroll") for (int r=0;r<4;++r) \
                       out[ob + (size_t)(4*lg+r)*ND + d] = ys[r]; } \
            _Pragma("unroll") for (int r=0;r<4;++r) PACKX(xn[r], r) \
            BSYNC();  /* barB: xP ready */ }
            G2EVAL(1)
            G2EVAL(2)
            G2EVAL(3)
            G2EVAL(4)
        }
    }
}

extern "C" void kernel_launch(void* const* d_in, const int* in_sizes, int n_in,
                              void* d_out, int out_size, void* d_ws, size_t ws_size,
                              hipStream_t stream) {
    const float* y0 = (const float*)d_in[0];
    const float* t  = (const float*)d_in[1];
    const float* W1 = (const float*)d_in[2];
    const float* b1 = (const float*)d_in[3];
    const float* W2 = (const float*)d_in[4];
    const float* b2 = (const float*)d_in[5];
    float* out = (float*)d_out;
    int nsteps = in_sizes[1] - 1;
    hipLaunchKernelGGL(node_rk4_mfma, dim3(NBLK), dim3(NTHR), 0, stream,
                       y0, t, W1, b1, W2, b2, out, nsteps);
}

// Round 20
// 4673.623 us; speedup vs baseline: 1.2736x; 1.0911x over previous
//
#include <hip/hip_runtime.h>

// r20: VALU dual-chain software pipeline. r15's wave-specialized structure
// (G1-waves: W1-cols, integrate+GEMM1+tanh; G2-waves: W2-rows, GEMM2
// partials) was issue-optimal in busy cycles (1080cy/SIMD/eval ~= the 1046cy
// FLOP floor) but 31% idle: 2-phase ping-pong on ONE chain leaves half the
// waves at a barrier each phase. r20: block owns TWO independent rows
// (chains A,B); each slot G1 serves one chain while G2 serves the other ->
// all 8 waves busy every slot; 1 barrier/slot; 8 slots per RK4 step for
// BOTH chains. Same math, weights, stride-5 partials as r15 (proven).

#define NB 1024
#define ND 64
#define NH 256
#define NBLK 512     // 2 rows per block
#define NTHR 512     // 8 waves: 4x G1 + 4x G2

// LDS float offsets (1664 floats = 6.5 KB)
#define XBOF(C,W) (((C)<<8) + ((W)<<6))   // xb[2][4][64]  per-chain per-G1-wave x bcast
#define ABOF(C)   (512 + ((C)<<8))        // ab[2][256]    per-chain activations
#define PTOF(C)   (1024 + (C)*320)        // part[2][64*5] stride-5 partials

#define R64(M) M(0) M(1) M(2) M(3) M(4) M(5) M(6) M(7) M(8) M(9) \
  M(10) M(11) M(12) M(13) M(14) M(15) M(16) M(17) M(18) M(19) \
  M(20) M(21) M(22) M(23) M(24) M(25) M(26) M(27) M(28) M(29) \
  M(30) M(31) M(32) M(33) M(34) M(35) M(36) M(37) M(38) M(39) \
  M(40) M(41) M(42) M(43) M(44) M(45) M(46) M(47) M(48) M(49) \
  M(50) M(51) M(52) M(53) M(54) M(55) M(56) M(57) M(58) M(59) \
  M(60) M(61) M(62) M(63)

#define Q16(M) M(0,0,1,2,3) M(1,4,5,6,7) M(2,8,9,10,11) M(3,12,13,14,15) \
  M(4,16,17,18,19) M(5,20,21,22,23) M(6,24,25,26,27) M(7,28,29,30,31) \
  M(8,32,33,34,35) M(9,36,37,38,39) M(10,40,41,42,43) M(11,44,45,46,47) \
  M(12,48,49,50,51) M(13,52,53,54,55) M(14,56,57,58,59) M(15,60,61,62,63)

__device__ __forceinline__ float fast_tanh(float x) {
    float e = __expf(2.0f * x);
    float r = __builtin_amdgcn_rcpf(e + 1.0f);
    return 1.0f - 2.0f * r;
}

// lgkmcnt-only barrier: no vmcnt drain (out stores keep flowing).
#define BSYNC() do {                                             \
    asm volatile("s_waitcnt lgkmcnt(0)" ::: "memory");           \
    __builtin_amdgcn_s_barrier();                                \
    asm volatile("" ::: "memory");                               \
} while (0)

__global__ __launch_bounds__(NTHR, 4)
void node_rk4_kernel(const float* __restrict__ y0,
                     const float* __restrict__ t,
                     const float* W1,
                     const float* b1,
                     const float* W2,
                     const float* b2,
                     float* __restrict__ out,
                     int nsteps)
{
    __shared__ float lds[1664];
    const int tid = threadIdx.x;
    const int w   = tid >> 6;        // wave 0..7
    const int l   = tid & 63;        // lane

    if (w < 4) {
        // ===== G1: integrate + GEMM1 + tanh (chain-alternating) =====
        const int j = (w << 6) + l;            // owned hidden unit
        const float b1l = b1[j];
        const float b2l = b2[l];
        #define DW1(i) float w1_##i;
        R64(DW1)
        #define LW1(i) w1_##i = W1[(i) * NH + j];
        R64(LW1)

        float* xbwA = lds + XBOF(0, w);
        float* xbwB = lds + XBOF(1, w);
        const float4* xqA = (const float4*)xbwA;
        const float4* xqB = (const float4*)xbwB;
        float* abA = lds + ABOF(0) + (w << 6);
        float* abB = lds + ABOF(1) + (w << 6);
        const float* prA = lds + PTOF(0);
        const float* prB = lds + PTOF(1);

        const int row0 = blockIdx.x * 2;
        float yA = y0[(row0 + 0) * ND + l];
        float yB = y0[(row0 + 1) * ND + l];
        float kaA = 0.0f, kaB = 0.0f;
        if (w == 0) {
            out[(size_t)(row0 + 0) * ND + l] = yA;   // step-0 output
            out[(size_t)(row0 + 1) * ND + l] = yB;
        }
        float dt = 0.0f, dt2 = 0.0f, dt6 = 0.0f;
        size_t obase = 0;

#define G1Q(q,i0,i1,i2,i3) { float4 xv_ = xq_[q]; \
    h0_ = fmaf(w1_##i0, xv_.x, h0_); h1_ = fmaf(w1_##i1, xv_.y, h1_); \
    h0_ = fmaf(w1_##i2, xv_.z, h0_); h1_ = fmaf(w1_##i3, xv_.w, h1_); }

// One G1 slot for chain C: finalize stage ST's k (ST=0: init, x=y0),
// RK4-advance x, then GEMM1+tanh -> ab[C]. In-wave x roundtrip via lgkm.
#define G1SLOT(C, CI, ST) do {                                       \
    float x_;                                                        \
    if ((ST) == 0) { x_ = y##C; }                                    \
    else {                                                           \
      const float* pr_ = pr##C + l * 5;                              \
      float kc_ = ((pr_[0] + pr_[1]) + (pr_[2] + pr_[3])) + b2l;     \
      if ((ST)==1)      { ka##C  = kc_;       x_ = fmaf(dt2, kc_, y##C); } \
      else if ((ST)==2) { ka##C += 2.0f*kc_;  x_ = fmaf(dt2, kc_, y##C); } \
      else if ((ST)==3) { ka##C += 2.0f*kc_;  x_ = fmaf(dt,  kc_, y##C); } \
      else { y##C = fmaf(dt6, ka##C + kc_, y##C); x_ = y##C;         \
             if (w == 0) out[obase + (CI) * ND + l] = y##C; }        \
    }                                                                \
    xbw##C[l] = x_;                                                  \
    asm volatile("s_waitcnt lgkmcnt(0)" ::: "memory");               \
    const float4* xq_ = xq##C;                                       \
    float h0_ = b1l, h1_ = 0.0f;                                     \
    Q16(G1Q)                                                         \
    ab##C[l] = fast_tanh(h0_ + h1_);                                 \
} while (0)

        G1SLOT(A, 0, 0); BSYNC();     // slot 0
        G1SLOT(B, 1, 0); BSYNC();     // slot 1
        for (int s = 0; s < nsteps; ++s) {
            dt = t[s + 1] - t[s]; dt2 = 0.5f * dt; dt6 = dt * (1.0f / 6.0f);
            obase = (size_t)(s + 1) * (NB * ND) + (size_t)row0 * ND;
            G1SLOT(A, 0, 1); BSYNC();  G1SLOT(B, 1, 1); BSYNC();
            G1SLOT(A, 0, 2); BSYNC();  G1SLOT(B, 1, 2); BSYNC();
            G1SLOT(A, 0, 3); BSYNC();  G1SLOT(B, 1, 3); BSYNC();
            G1SLOT(A, 0, 4); BSYNC();  G1SLOT(B, 1, 4); BSYNC();
        }
        // last (A,4)/(B,4) slots emit one harmless extra GEMM1 each
        // (consumed never / by G2's final harmless slot).
    } else {
        // ===== G2: GEMM2 partials (chain-alternating, stage-agnostic) =====
        const int jj = w - 4;                  // owned j-slice [64jj,64jj+64)
        #define DW2(i) float w2_##i;
        R64(DW2)
        #define LW2(i) w2_##i = W2[((jj << 6) + (i)) * ND + l];
        R64(LW2)

        const float4* aqA = (const float4*)(lds + ABOF(0) + (jj << 6));
        const float4* aqB = (const float4*)(lds + ABOF(1) + (jj << 6));
        float* pwA = lds + PTOF(0);
        float* pwB = lds + PTOF(1);

#define G2Q(q,i0,i1,i2,i3) { float4 av_ = aq_[q]; \
    p0_ = fmaf(w2_##i0, av_.x, p0_); p1_ = fmaf(w2_##i1, av_.y, p1_); \
    p0_ = fmaf(w2_##i2, av_.z, p0_); p1_ = fmaf(w2_##i3, av_.w, p1_); }

#define G2SLOT(C) do {                                               \
    const float4* aq_ = aq##C;                                       \
    float p0_ = 0.0f, p1_ = 0.0f;                                    \
    Q16(G2Q)                                                         \
    pw##C[l * 5 + jj] = p0_ + p1_;   /* stride-5: conflict-free */   \
} while (0)

        BSYNC();                      // slot 0 (idle)
        G2SLOT(A); BSYNC();           // slot 1: A's k1
        for (int s = 0; s < nsteps; ++s) {
            G2SLOT(B); BSYNC();  G2SLOT(A); BSYNC();
            G2SLOT(B); BSYNC();  G2SLOT(A); BSYNC();
            G2SLOT(B); BSYNC();  G2SLOT(A); BSYNC();
            G2SLOT(B); BSYNC();  G2SLOT(A); BSYNC();
        }
    }
}

extern "C" void kernel_launch(void* const* d_in, const int* in_sizes, int n_in,
                              void* d_out, int out_size, void* d_ws, size_t ws_size,
                              hipStream_t stream) {
    const float* y0 = (const float*)d_in[0];
    const float* t  = (const float*)d_in[1];
    const float* W1 = (const float*)d_in[2];
    const float* b1 = (const float*)d_in[3];
    const float* W2 = (const float*)d_in[4];
    const float* b2 = (const float*)d_in[5];
    float* out = (float*)d_out;
    int nsteps = in_sizes[1] - 1;
    hipLaunchKernelGGL(node_rk4_kernel, dim3(NBLK), dim3(NTHR), 0, stream,
                       y0, t, W1, b1, W2, b2, out, nsteps);
}